// Round 11
// baseline (309.164 us; speedup 1.0000x reference)
//
#include <hip/hip_runtime.h>
#include <hip/hip_fp16.h>

// ---------------- workspace layout (float offsets) ----------------
constexpr size_t OFF_Y0    = 0;         // 8*16*128*128 = 2097152
constexpr size_t OFF_Y1    = 2097152;   // 8*32*64*64   = 1048576
constexpr size_t OFF_Y2    = 3145728;   // 8*64*32*32   = 524288
constexpr size_t OFF_Y3    = 3670016;   // 8*128*16*16  = 262144 (ends 3932160)
constexpr size_t OFF_U     = 3670016;   // 8*15*1089 = 130680 (in dead Y3, after conv4 reads it)
constexpr size_t OFF_LUT64 = 0;         // 8*35937*16 dwords = 4599936 (overlaps dead Y0/Y1)
constexpr size_t OFF_STATB = 4926640;
constexpr size_t OFF_STAT0 = OFF_STATB + 0;     // 8*16*2  = 256
constexpr size_t OFF_STAT1 = OFF_STATB + 256;   // 8*32*2  = 512
constexpr size_t OFF_STAT2 = OFF_STATB + 768;   // 8*64*2  = 1024
constexpr size_t OFF_STAT3 = OFF_STATB + 1792;  // 8*128*2 = 2048
constexpr size_t OFF_FEATS = OFF_STATB + 3840;  // 8*128   = 1024

__global__ __launch_bounds__(256) void zero_k(float* __restrict__ p, int n) {
  int i = blockIdx.x*256 + threadIdx.x;
  if (i < n) p[i] = 0.f;
}

// ---------------- unified tiled conv: stride-2 3x3 + lrelu (+stats / +mean) ----------------
template<int CIN, int COUT, int HIN, int WIN, int TH, int OCG, int PX, int OCT,
         int BLK, int MODE, int NPXPREV>
__global__ __launch_bounds__(BLK) void conv_tile(
    const float* __restrict__ xin, const float* __restrict__ wgt,
    const float* __restrict__ bias, const float* __restrict__ stat_in,
    const float* __restrict__ gam, const float* __restrict__ bet,
    float* __restrict__ yout, float* __restrict__ stat_out)
{
  constexpr int HOUT = HIN/2, WOUT = WIN/2;
  constexpr int SEG  = WOUT + 4;
  constexpr int XROW = 2*SEG;
  constexpr int XPI  = (2*TH+1)*XROW;
  constexpr int NT   = HOUT/TH;
  constexpr int NSTRIP_B = TH*WOUT/PX;
  constexpr int GPT  = OCG/OCT;
  static_assert(BLK == NSTRIP_B*GPT, "thread mapping mismatch");
  constexpr int R = NSTRIP_B < 64 ? NSTRIP_B : 64;

  __shared__ __align__(16) float xs[CIN*XPI];
  __shared__ float s_sc[CIN], s_sf[CIN];

  const int tid = threadIdx.x;
  const int lin = blockIdx.x;
  const int b = lin & 7;
  const int r2 = lin >> 3;
  const int tile = r2 % NT;
  const int ocb  = r2 / NT;

  if constexpr (MODE == 0) {
    if (tid == 0)      { s_sc[0] = 1.f/0.229f; s_sf[0] = -0.485f/0.229f; }
    else if (tid == 1) { s_sc[1] = 1.f/0.224f; s_sf[1] = -0.456f/0.224f; }
    else if (tid == 2) { s_sc[2] = 1.f/0.225f; s_sf[2] = -0.406f/0.225f; }
  } else {
    if (tid < CIN) {
      float S = stat_in[(b*CIN+tid)*2+0], Q = stat_in[(b*CIN+tid)*2+1];
      float mean = S*(1.0f/NPXPREV);
      float var  = Q*(1.0f/NPXPREV) - mean*mean;
      float rstd = rsqrtf(var + 1e-5f);
      float gg = gam[tid], bb = bet[tid];
      s_sc[tid] = gg*rstd;
      s_sf[tid] = bb - mean*gg*rstd;
    }
  }
  __syncthreads();

  const int iy0 = tile*(2*TH) - 1;
  const float* xb_g = xin + (size_t)b*CIN*HIN*WIN;
  for (int e = tid; e < CIN*(2*TH+1)*(WIN+2); e += BLK) {
    int ic  = e / ((2*TH+1)*(WIN+2));
    int rem = e - ic*((2*TH+1)*(WIN+2));
    int rr  = rem / (WIN+2);
    int cc  = rem - rr*(WIN+2);
    int iy = iy0 + rr, ix = cc - 1;
    float v = 0.f;
    if (iy >= 0 && iy < HIN && ix >= 0 && ix < WIN)
      v = s_sc[ic]*xb_g[(size_t)ic*HIN*WIN + iy*WIN + ix] + s_sf[ic];
    int off = (ix & 1) ? (SEG + ((ix+1) >> 1)) : (ix >> 1);
    xs[ic*XPI + rr*XROW + off] = v;
  }
  __syncthreads();

  const int s  = tid % NSTRIP_B;
  const int g  = tid / NSTRIP_B;
  const int r  = s / (WOUT/PX);
  const int c0 = (s % (WOUT/PX)) * PX;
  const int oc0 = ocb*OCG + g*OCT;

  float acc[OCT][PX];
  #pragma unroll
  for (int k = 0; k < OCT; ++k) {
    float bb = bias[oc0+k];
    #pragma unroll
    for (int j = 0; j < PX; ++j) acc[k][j] = bb;
  }

  float wv[OCT][9];
  #pragma unroll
  for (int k = 0; k < OCT; ++k) {
    const float* wp = wgt + ((size_t)(oc0+k)*CIN)*9;
    #pragma unroll
    for (int t = 0; t < 9; ++t) wv[k][t] = wp[t];
  }

  for (int ic = 0; ic < CIN; ++ic) {
    float wn[OCT][9];
    if (ic + 1 < CIN) {
      #pragma unroll
      for (int k = 0; k < OCT; ++k) {
        const float* wp = wgt + ((size_t)(oc0+k)*CIN + ic + 1)*9;
        #pragma unroll
        for (int t = 0; t < 9; ++t) wn[k][t] = wp[t];
      }
    }
    const float* xb = xs + ic*XPI;
    #pragma unroll
    for (int ky = 0; ky < 3; ++ky) {
      const float* rowp = xb + (2*r+ky)*XROW;
      float eb[PX], ob[PX+1];
      if constexpr (PX == 8) {
        *(float4*)&eb[0] = *(const float4*)(rowp + c0);
        *(float4*)&eb[4] = *(const float4*)(rowp + c0 + 4);
        *(float4*)&ob[0] = *(const float4*)(rowp + SEG + c0);
        *(float4*)&ob[4] = *(const float4*)(rowp + SEG + c0 + 4);
        ob[8] = rowp[SEG + c0 + 8];
      } else if constexpr (PX == 4) {
        *(float4*)&eb[0] = *(const float4*)(rowp + c0);
        *(float4*)&ob[0] = *(const float4*)(rowp + SEG + c0);
        ob[4] = rowp[SEG + c0 + 4];
      } else if constexpr (PX == 2) {
        *(float2*)&eb[0] = *(const float2*)(rowp + c0);
        *(float2*)&ob[0] = *(const float2*)(rowp + SEG + c0);
        ob[2] = rowp[SEG + c0 + 2];
      } else {
        eb[0] = rowp[c0];
        ob[0] = rowp[SEG + c0];
        ob[1] = rowp[SEG + c0 + 1];
      }
      #pragma unroll
      for (int k = 0; k < OCT; ++k) {
        float w0 = wv[k][ky*3], w1 = wv[k][ky*3+1], w2 = wv[k][ky*3+2];
        #pragma unroll
        for (int j = 0; j < PX; ++j)
          acc[k][j] += w0*ob[j] + w1*eb[j] + w2*ob[j+1];
      }
    }
    if (ic + 1 < CIN) {
      #pragma unroll
      for (int k = 0; k < OCT; ++k)
        #pragma unroll
        for (int t = 0; t < 9; ++t) wv[k][t] = wn[k][t];
    }
  }

  const int oy = tile*TH + r;
  if constexpr (MODE != 2) {
    float lsum[OCT], lsq[OCT];
    #pragma unroll
    for (int k = 0; k < OCT; ++k) {
      float ov[PX];
      float ls = 0.f, lq = 0.f;
      #pragma unroll
      for (int j = 0; j < PX; ++j) {
        float a = acc[k][j];
        a = a >= 0.f ? a : 0.2f*a;
        ov[j] = a; ls += a; lq += a*a;
      }
      lsum[k] = ls; lsq[k] = lq;
      float* yp = yout + (((size_t)b*COUT + oc0 + k)*HOUT + oy)*WOUT + c0;
      if constexpr (PX == 8) {
        *(float4*)yp = *(float4*)&ov[0];
        *(float4*)(yp+4) = *(float4*)&ov[4];
      } else if constexpr (PX == 4) {
        *(float4*)yp = *(float4*)&ov[0];
      } else if constexpr (PX == 2) {
        *(float2*)yp = *(float2*)&ov[0];
      } else {
        *yp = ov[0];
      }
    }
    #pragma unroll
    for (int k = 0; k < OCT; ++k) {
      #pragma unroll
      for (int off = R/2; off > 0; off >>= 1) {
        lsum[k] += __shfl_down(lsum[k], off);
        lsq[k]  += __shfl_down(lsq[k],  off);
      }
    }
    if ((tid & (R-1)) == 0) {
      #pragma unroll
      for (int k = 0; k < OCT; ++k) {
        atomicAdd(&stat_out[(b*COUT + oc0 + k)*2 + 0], lsum[k]);
        atomicAdd(&stat_out[(b*COUT + oc0 + k)*2 + 1], lsq[k]);
      }
    }
  } else {
    float a = acc[0][0];
    a = a >= 0.f ? a : 0.2f*a;
    #pragma unroll
    for (int off = R/2; off > 0; off >>= 1) a += __shfl_down(a, off);
    if ((tid & (R-1)) == 0) atomicAdd(&stat_out[b*COUT + oc0], a);
  }
}

// ---------------- U direct: head (redundant per block) + V fold + U slice ----------------
__global__ __launch_bounds__(256) void u_direct_kernel(
    const float* __restrict__ featsum, const float* __restrict__ w0, const float* __restrict__ b0,
    const float* __restrict__ w1, const float* __restrict__ b1,
    const float* __restrict__ luts, const float* __restrict__ wl, float* __restrict__ U)
{
  __shared__ float sh_h[128];
  __shared__ float sh_w[20];
  __shared__ float sh_v[20];
  const int tid = threadIdx.x;
  const int lin = blockIdx.x;            // bt + 8*(j*5+qb), 600 blocks
  const int bt = lin & 7;
  const int rest = lin >> 3;             // 0..74
  const int j = rest / 5, qb = rest % 5;
  const int s = j / 3, ch = j % 3;

  if (tid < 128) {
    const float* f = featsum + bt*128;
    const float* w = w0 + tid*128;
    float a = 0.f;
    for (int k = 0; k < 128; ++k) a += f[k]*w[k];
    a = b0[tid] + a*(1.0f/64.0f);
    float c = fminf(fmaxf(a + 3.f, 0.f), 6.f);
    sh_h[tid] = a * c * (1.f/6.f);
  }
  __syncthreads();
  if (tid < 20) {
    const float* w = w1 + tid*128;
    float a = b1[tid];
    for (int k = 0; k < 128; ++k) a += sh_h[k]*w[k];
    sh_w[tid] = a;
  }
  __syncthreads();
  if (tid < 20) {
    float a = 0.f;
    #pragma unroll
    for (int n = 0; n < 20; ++n)
      a += sh_w[n] * luts[(s*60 + n*3 + ch)*20 + tid];
    sh_v[tid] = a;
  }
  __syncthreads();
  const int q = qb*256 + tid;
  if (q < 1089) {
    float a = 0.f;
    #pragma unroll
    for (int w = 0; w < 20; ++w) a += sh_v[w] * wl[w*1089 + q];
    U[(size_t)(bt*15 + j)*1089 + q] = a;
  }
}

// ---------------- fused lutc+expand: block = (bt, bi-plane), both planes in LDS -------------
__global__ __launch_bounds__(256) void lut_fuse_kernel(
    const float* __restrict__ U, const float* __restrict__ slay, uint4* __restrict__ lut64)
{
  __shared__ uint2 s_lutc[2*1089];
  __shared__ float s_slay[165];
  const int tid = threadIdx.x;
  const int lin = blockIdx.x;            // bt + 8*bi, 264 blocks
  const int bt = lin & 7;
  const int bi = lin >> 3;               // 0..32
  if (tid < 165) s_slay[tid] = slay[tid];
  __syncthreads();
  const float* Ub = U + (size_t)bt*15*1089;
  for (int e = tid; e < 2*1089; e += 256) {
    int p = e / 1089, idx = e - p*1089;
    int bb = bi + p; if (bb > 32) bb = 32;
    int gi = idx / 33, ri = idx - gi*33;
    float v0 = 0.f, v1 = 0.f, v2 = 0.f;
    #pragma unroll
    for (int s = 0; s < 5; ++s) {
      v0 += s_slay[ri*5+s] * Ub[(s*3+0)*1089 + bb*33 + gi];
      v1 += s_slay[gi*5+s] * Ub[(s*3+1)*1089 + bb*33 + ri];
      v2 += s_slay[bb*5+s] * Ub[(s*3+2)*1089 + gi*33 + ri];
    }
    union { __half2 h2; unsigned u; } p0, p1;
    p0.h2 = __floats2half2_rn(v0, v1);
    p1.h2 = __floats2half2_rn(v2, 0.f);
    s_lutc[e] = make_uint2(p0.u, p1.u);
  }
  __syncthreads();
  for (int e = tid; e < 1089; e += 256) {
    int gi = e / 33, ri = e - gi*33;
    int g1 = gi < 32 ? gi+1 : 32, r1 = ri < 32 ? ri+1 : 32;
    union { unsigned short h[32]; uint4 q[4]; } u;
    #pragma unroll
    for (int t = 24; t < 32; ++t) u.h[t] = 0;
    const int gsel[2] = { gi, g1 }, rsel[2] = { ri, r1 };
    #pragma unroll
    for (int db = 0; db < 2; ++db)
      #pragma unroll
      for (int dg = 0; dg < 2; ++dg)
        #pragma unroll
        for (int dr = 0; dr < 2; ++dr) {
          const int idx = db*4 + dg*2 + dr;
          uint2 sv = s_lutc[db*1089 + gsel[dg]*33 + rsel[dr]];
          u.h[idx*3+0] = (unsigned short)(sv.x & 0xffff);
          u.h[idx*3+1] = (unsigned short)(sv.x >> 16);
          u.h[idx*3+2] = (unsigned short)(sv.y & 0xffff);
        }
    uint4* dst = lut64 + ((size_t)bt*35937 + bi*1089 + e)*4;
    dst[0] = u.q[0]; dst[1] = u.q[1]; dst[2] = u.q[2]; dst[3] = u.q[3];
  }
}

// ---------------- trilinear apply + residual: 8 px/thread, 512-thread blocks ----------------
__global__ __launch_bounds__(512) void trilin_kernel(
    const float* __restrict__ img, const uint4* __restrict__ lut, float* __restrict__ out)
{
  constexpr int NPX = 720*1280;
  const int lin = blockIdx.x;
  const int bt = lin & 7;
  const int v = (lin >> 3)*512 + threadIdx.x;   // < NPX/8 exactly (225*512)
  const float* ib = img + (size_t)bt*3*NPX;
  float4 rc[2], gc[2], bc[2];
  rc[0] = ((const float4*)ib)[2*v];             rc[1] = ((const float4*)ib)[2*v+1];
  gc[0] = ((const float4*)(ib + NPX))[2*v];     gc[1] = ((const float4*)(ib + NPX))[2*v+1];
  bc[0] = ((const float4*)(ib + 2*NPX))[2*v];   bc[1] = ((const float4*)(ib + 2*NPX))[2*v+1];
  const uint4* L = lut + (size_t)bt*35937*4;
  const float invbin = 32.0f/1.000001f;

  int base[8];
  float fr[8], fg[8], fb[8];
  #pragma unroll
  for (int j = 0; j < 8; ++j) {
    float r = ((float*)&rc[0])[j], g = ((float*)&gc[0])[j], b = ((float*)&bc[0])[j];
    float pr = r*invbin, pg = g*invbin, pb = b*invbin;
    int ri = (int)pr; ri = ri > 31 ? 31 : ri; ri = ri < 0 ? 0 : ri;
    int gi = (int)pg; gi = gi > 31 ? 31 : gi; gi = gi < 0 ? 0 : gi;
    int bi = (int)pb; bi = bi > 31 ? 31 : bi; bi = bi < 0 ? 0 : bi;
    fr[j] = pr - ri; fg[j] = pg - gi; fb[j] = pb - bi;
    base[j] = (bi*33 + gi)*33 + ri;
  }
  uint4 q0[8], q1[8], q2[8];
  #pragma unroll
  for (int j = 0; j < 8; ++j) {
    const uint4* e = L + (size_t)base[j]*4;
    q0[j] = e[0]; q1[j] = e[1]; q2[j] = e[2];
  }
  float4 ro[2], go[2], bo[2];
  #pragma unroll
  for (int j = 0; j < 8; ++j) {
    union { uint4 q[3]; __half h[24]; } u;
    u.q[0] = q0[j]; u.q[1] = q1[j]; u.q[2] = q2[j];
    float wr1 = fr[j], wr0 = 1.f-fr[j];
    float wg1 = fg[j], wg0 = 1.f-fg[j];
    float wb1 = fb[j], wb0 = 1.f-fb[j];
    float w00 = wb0*wg0, w01 = wb0*wg1, w10 = wb1*wg0, w11 = wb1*wg1;
    float wt[8] = { w00*wr0, w00*wr1, w01*wr0, w01*wr1,
                    w10*wr0, w10*wr1, w11*wr0, w11*wr1 };
    float rr = 0.f, gg = 0.f, bb2 = 0.f;
    #pragma unroll
    for (int idx = 0; idx < 8; ++idx) {
      float wv = wt[idx];
      rr  += wv * __half2float(u.h[idx*3+0]);
      gg  += wv * __half2float(u.h[idx*3+1]);
      bb2 += wv * __half2float(u.h[idx*3+2]);
    }
    ((float*)&ro[0])[j] = rr  + ((float*)&rc[0])[j];
    ((float*)&go[0])[j] = gg  + ((float*)&gc[0])[j];
    ((float*)&bo[0])[j] = bb2 + ((float*)&bc[0])[j];
  }
  float* ob = out + (size_t)bt*3*NPX;
  ((float4*)ob)[2*v]             = ro[0]; ((float4*)ob)[2*v+1]             = ro[1];
  ((float4*)(ob + NPX))[2*v]     = go[0]; ((float4*)(ob + NPX))[2*v+1]     = go[1];
  ((float4*)(ob + 2*NPX))[2*v]   = bo[0]; ((float4*)(ob + 2*NPX))[2*v+1]   = bo[1];
}

// ---------------- launcher ----------------
extern "C" void kernel_launch(void* const* d_in, const int* in_sizes, int n_in,
                              void* d_out, int out_size, void* d_ws, size_t ws_size,
                              hipStream_t stream) {
  const float* img     = (const float*)d_in[0];
  const float* img_org = (const float*)d_in[1];
  const float* c0w = (const float*)d_in[2];  const float* c0b = (const float*)d_in[3];
  const float* c1w = (const float*)d_in[4];  const float* c1b = (const float*)d_in[5];
  const float* c2w = (const float*)d_in[6];  const float* c2b = (const float*)d_in[7];
  const float* c3w = (const float*)d_in[8];  const float* c3b = (const float*)d_in[9];
  const float* c4w = (const float*)d_in[10]; const float* c4b = (const float*)d_in[11];
  const float* n0g = (const float*)d_in[12]; const float* n0b = (const float*)d_in[13];
  const float* n1g = (const float*)d_in[14]; const float* n1b = (const float*)d_in[15];
  const float* n2g = (const float*)d_in[16]; const float* n2b = (const float*)d_in[17];
  const float* n3g = (const float*)d_in[18]; const float* n3b = (const float*)d_in[19];
  const float* cls0_w = (const float*)d_in[20]; const float* cls0_b = (const float*)d_in[21];
  const float* cls1_w = (const float*)d_in[22]; const float* cls1_b = (const float*)d_in[23];
  const float* s_layers = (const float*)d_in[24];
  const float* w_layers = (const float*)d_in[25];
  const float* luts     = (const float*)d_in[26];
  float* ws = (float*)d_ws;
  float* out = (float*)d_out;

  // zero stats + featsum
  zero_k<<<19, 256, 0, stream>>>(ws + OFF_STATB, 4864);

  // conv0: 3->16.  TH=4 OCG=8  PX=8 OCT=1 -> BLK=512, grid 8*32*2 = 512 (2 blocks/CU)
  conv_tile<3,16,256,256, 4,8, 8,1, 512, 0, 1><<<512, 512, 0, stream>>>(
      img, c0w, c0b, nullptr, nullptr, nullptr, ws + OFF_Y0, ws + OFF_STAT0);
  // conv1: 16->32. TH=2 OCG=16 PX=4 OCT=1 -> BLK=512, grid 8*32*2 = 512
  conv_tile<16,32,128,128, 2,16, 4,1, 512, 1, 16384><<<512, 512, 0, stream>>>(
      ws + OFF_Y0, c1w, c1b, ws + OFF_STAT0, n0g, n0b, ws + OFF_Y1, ws + OFF_STAT1);
  // conv2: 32->64. TH=2 OCG=16 PX=2 OCT=1 -> BLK=512, grid 8*16*4 = 512
  conv_tile<32,64,64,64, 2,16, 2,1, 512, 1, 4096><<<512, 512, 0, stream>>>(
      ws + OFF_Y1, c2w, c2b, ws + OFF_STAT1, n1g, n1b, ws + OFF_Y2, ws + OFF_STAT2);
  // conv3: 64->128. TH=2 OCG=16 PX=1 OCT=1 -> BLK=512, grid 8*8*8 = 512
  conv_tile<64,128,32,32, 2,16, 1,1, 512, 1, 1024><<<512, 512, 0, stream>>>(
      ws + OFF_Y2, c3w, c3b, ws + OFF_STAT2, n2g, n2b, ws + OFF_Y3, ws + OFF_STAT3);
  // conv4: 128->128, mean -> featsum. TH=2 OCG=16 PX=1 OCT=1 -> BLK=256, grid 256
  conv_tile<128,128,16,16, 2,16, 1,1, 256, 2, 256><<<256, 256, 0, stream>>>(
      ws + OFF_Y3, c4w, c4b, ws + OFF_STAT3, n3g, n3b, nullptr, ws + OFF_FEATS);

  // U directly from luts/wl with in-block head
  u_direct_kernel<<<600, 256, 0, stream>>>(
      ws + OFF_FEATS, cls0_w, cls0_b, cls1_w, cls1_b,
      luts, w_layers, ws + OFF_U);

  // fused lutc + expand
  lut_fuse_kernel<<<264, 256, 0, stream>>>(
      ws + OFF_U, s_layers, (uint4*)(ws + OFF_LUT64));

  trilin_kernel<<<225*8, 512, 0, stream>>>(
      img_org, (const uint4*)(ws + OFF_LUT64), out);
}

// Round 12
// 266.599 us; speedup vs baseline: 1.1597x; 1.1597x over previous
//
#include <hip/hip_runtime.h>
#include <hip/hip_fp16.h>

// ---------------- workspace layout (float offsets) ----------------
constexpr size_t OFF_Y0    = 0;         // 8*16*128*128 = 2097152
constexpr size_t OFF_Y1    = 2097152;   // 8*32*64*64   = 1048576
constexpr size_t OFF_Y2    = 3145728;   // 8*64*32*32   = 524288
constexpr size_t OFF_Y3    = 3670016;   // 8*128*16*16  = 262144 (ends 3932160)
constexpr size_t OFF_U     = 3670016;   // 8*15*1089 = 130680 (in dead Y3, after conv4 reads it)
constexpr size_t OFF_LUT64 = 0;         // 8*35937*16 dwords = 4599936 (overlaps dead Y0/Y1)
constexpr size_t OFF_STATB = 4926640;
constexpr size_t OFF_STAT0 = OFF_STATB + 0;     // 8*16*2  = 256
constexpr size_t OFF_STAT1 = OFF_STATB + 256;   // 8*32*2  = 512
constexpr size_t OFF_STAT2 = OFF_STATB + 768;   // 8*64*2  = 1024
constexpr size_t OFF_STAT3 = OFF_STATB + 1792;  // 8*128*2 = 2048
constexpr size_t OFF_FEATS = OFF_STATB + 3840;  // 8*128   = 1024

__global__ __launch_bounds__(256) void zero_k(float* __restrict__ p, int n) {
  int i = blockIdx.x*256 + threadIdx.x;
  if (i < n) p[i] = 0.f;
}

// ---------------- unified tiled conv: stride-2 3x3 + lrelu (+stats / +mean) ----------------
template<int CIN, int COUT, int HIN, int WIN, int TH, int OCG, int PX, int OCT,
         int BLK, int MODE, int NPXPREV>
__global__ __launch_bounds__(BLK) void conv_tile(
    const float* __restrict__ xin, const float* __restrict__ wgt,
    const float* __restrict__ bias, const float* __restrict__ stat_in,
    const float* __restrict__ gam, const float* __restrict__ bet,
    float* __restrict__ yout, float* __restrict__ stat_out)
{
  constexpr int HOUT = HIN/2, WOUT = WIN/2;
  constexpr int SEG  = WOUT + 4;
  constexpr int XROW = 2*SEG;
  constexpr int XPI  = (2*TH+1)*XROW;
  constexpr int NT   = HOUT/TH;
  constexpr int NSTRIP_B = TH*WOUT/PX;
  constexpr int GPT  = OCG/OCT;
  static_assert(BLK == NSTRIP_B*GPT, "thread mapping mismatch");
  constexpr int R = NSTRIP_B < 64 ? NSTRIP_B : 64;

  __shared__ __align__(16) float xs[CIN*XPI];
  __shared__ float s_sc[CIN], s_sf[CIN];

  const int tid = threadIdx.x;
  const int lin = blockIdx.x;
  const int b = lin & 7;
  const int r2 = lin >> 3;
  const int tile = r2 % NT;
  const int ocb  = r2 / NT;

  if constexpr (MODE == 0) {
    if (tid == 0)      { s_sc[0] = 1.f/0.229f; s_sf[0] = -0.485f/0.229f; }
    else if (tid == 1) { s_sc[1] = 1.f/0.224f; s_sf[1] = -0.456f/0.224f; }
    else if (tid == 2) { s_sc[2] = 1.f/0.225f; s_sf[2] = -0.406f/0.225f; }
  } else {
    if (tid < CIN) {
      float S = stat_in[(b*CIN+tid)*2+0], Q = stat_in[(b*CIN+tid)*2+1];
      float mean = S*(1.0f/NPXPREV);
      float var  = Q*(1.0f/NPXPREV) - mean*mean;
      float rstd = rsqrtf(var + 1e-5f);
      float gg = gam[tid], bb = bet[tid];
      s_sc[tid] = gg*rstd;
      s_sf[tid] = bb - mean*gg*rstd;
    }
  }
  __syncthreads();

  const int iy0 = tile*(2*TH) - 1;
  const float* xb_g = xin + (size_t)b*CIN*HIN*WIN;
  for (int e = tid; e < CIN*(2*TH+1)*(WIN+2); e += BLK) {
    int ic  = e / ((2*TH+1)*(WIN+2));
    int rem = e - ic*((2*TH+1)*(WIN+2));
    int rr  = rem / (WIN+2);
    int cc  = rem - rr*(WIN+2);
    int iy = iy0 + rr, ix = cc - 1;
    float v = 0.f;
    if (iy >= 0 && iy < HIN && ix >= 0 && ix < WIN)
      v = s_sc[ic]*xb_g[(size_t)ic*HIN*WIN + iy*WIN + ix] + s_sf[ic];
    int off = (ix & 1) ? (SEG + ((ix+1) >> 1)) : (ix >> 1);
    xs[ic*XPI + rr*XROW + off] = v;
  }
  __syncthreads();

  const int s  = tid % NSTRIP_B;
  const int g  = tid / NSTRIP_B;
  const int r  = s / (WOUT/PX);
  const int c0 = (s % (WOUT/PX)) * PX;
  const int oc0 = ocb*OCG + g*OCT;

  float acc[OCT][PX];
  #pragma unroll
  for (int k = 0; k < OCT; ++k) {
    float bb = bias[oc0+k];
    #pragma unroll
    for (int j = 0; j < PX; ++j) acc[k][j] = bb;
  }

  float wv[OCT][9];
  #pragma unroll
  for (int k = 0; k < OCT; ++k) {
    const float* wp = wgt + ((size_t)(oc0+k)*CIN)*9;
    #pragma unroll
    for (int t = 0; t < 9; ++t) wv[k][t] = wp[t];
  }

  for (int ic = 0; ic < CIN; ++ic) {
    float wn[OCT][9];
    if (ic + 1 < CIN) {
      #pragma unroll
      for (int k = 0; k < OCT; ++k) {
        const float* wp = wgt + ((size_t)(oc0+k)*CIN + ic + 1)*9;
        #pragma unroll
        for (int t = 0; t < 9; ++t) wn[k][t] = wp[t];
      }
    }
    const float* xb = xs + ic*XPI;
    #pragma unroll
    for (int ky = 0; ky < 3; ++ky) {
      const float* rowp = xb + (2*r+ky)*XROW;
      float eb[PX], ob[PX+1];
      if constexpr (PX == 8) {
        *(float4*)&eb[0] = *(const float4*)(rowp + c0);
        *(float4*)&eb[4] = *(const float4*)(rowp + c0 + 4);
        *(float4*)&ob[0] = *(const float4*)(rowp + SEG + c0);
        *(float4*)&ob[4] = *(const float4*)(rowp + SEG + c0 + 4);
        ob[8] = rowp[SEG + c0 + 8];
      } else if constexpr (PX == 4) {
        *(float4*)&eb[0] = *(const float4*)(rowp + c0);
        *(float4*)&ob[0] = *(const float4*)(rowp + SEG + c0);
        ob[4] = rowp[SEG + c0 + 4];
      } else if constexpr (PX == 2) {
        *(float2*)&eb[0] = *(const float2*)(rowp + c0);
        *(float2*)&ob[0] = *(const float2*)(rowp + SEG + c0);
        ob[2] = rowp[SEG + c0 + 2];
      } else {
        eb[0] = rowp[c0];
        ob[0] = rowp[SEG + c0];
        ob[1] = rowp[SEG + c0 + 1];
      }
      #pragma unroll
      for (int k = 0; k < OCT; ++k) {
        float w0 = wv[k][ky*3], w1 = wv[k][ky*3+1], w2 = wv[k][ky*3+2];
        #pragma unroll
        for (int j = 0; j < PX; ++j)
          acc[k][j] += w0*ob[j] + w1*eb[j] + w2*ob[j+1];
      }
    }
    if (ic + 1 < CIN) {
      #pragma unroll
      for (int k = 0; k < OCT; ++k)
        #pragma unroll
        for (int t = 0; t < 9; ++t) wv[k][t] = wn[k][t];
    }
  }

  const int oy = tile*TH + r;
  if constexpr (MODE != 2) {
    float lsum[OCT], lsq[OCT];
    #pragma unroll
    for (int k = 0; k < OCT; ++k) {
      float ov[PX];
      float ls = 0.f, lq = 0.f;
      #pragma unroll
      for (int j = 0; j < PX; ++j) {
        float a = acc[k][j];
        a = a >= 0.f ? a : 0.2f*a;
        ov[j] = a; ls += a; lq += a*a;
      }
      lsum[k] = ls; lsq[k] = lq;
      float* yp = yout + (((size_t)b*COUT + oc0 + k)*HOUT + oy)*WOUT + c0;
      if constexpr (PX == 8) {
        *(float4*)yp = *(float4*)&ov[0];
        *(float4*)(yp+4) = *(float4*)&ov[4];
      } else if constexpr (PX == 4) {
        *(float4*)yp = *(float4*)&ov[0];
      } else if constexpr (PX == 2) {
        *(float2*)yp = *(float2*)&ov[0];
      } else {
        *yp = ov[0];
      }
    }
    #pragma unroll
    for (int k = 0; k < OCT; ++k) {
      #pragma unroll
      for (int off = R/2; off > 0; off >>= 1) {
        lsum[k] += __shfl_down(lsum[k], off);
        lsq[k]  += __shfl_down(lsq[k],  off);
      }
    }
    if ((tid & (R-1)) == 0) {
      #pragma unroll
      for (int k = 0; k < OCT; ++k) {
        atomicAdd(&stat_out[(b*COUT + oc0 + k)*2 + 0], lsum[k]);
        atomicAdd(&stat_out[(b*COUT + oc0 + k)*2 + 1], lsq[k]);
      }
    }
  } else {
    float a = acc[0][0];
    a = a >= 0.f ? a : 0.2f*a;
    #pragma unroll
    for (int off = R/2; off > 0; off >>= 1) a += __shfl_down(a, off);
    if ((tid & (R-1)) == 0) atomicAdd(&stat_out[b*COUT + oc0], a);
  }
}

// ---------------- U direct: head (redundant per block) + V fold + U slice ----------------
__global__ __launch_bounds__(256) void u_direct_kernel(
    const float* __restrict__ featsum, const float* __restrict__ w0, const float* __restrict__ b0,
    const float* __restrict__ w1, const float* __restrict__ b1,
    const float* __restrict__ luts, const float* __restrict__ wl, float* __restrict__ U)
{
  __shared__ float sh_h[128];
  __shared__ float sh_w[20];
  __shared__ float sh_v[20];
  const int tid = threadIdx.x;
  const int lin = blockIdx.x;            // bt + 8*(j*5+qb), 600 blocks
  const int bt = lin & 7;
  const int rest = lin >> 3;             // 0..74
  const int j = rest / 5, qb = rest % 5;
  const int s = j / 3, ch = j % 3;

  if (tid < 128) {
    const float* f = featsum + bt*128;
    const float* w = w0 + tid*128;
    float a = 0.f;
    for (int k = 0; k < 128; ++k) a += f[k]*w[k];
    a = b0[tid] + a*(1.0f/64.0f);
    float c = fminf(fmaxf(a + 3.f, 0.f), 6.f);
    sh_h[tid] = a * c * (1.f/6.f);
  }
  __syncthreads();
  if (tid < 20) {
    const float* w = w1 + tid*128;
    float a = b1[tid];
    for (int k = 0; k < 128; ++k) a += sh_h[k]*w[k];
    sh_w[tid] = a;
  }
  __syncthreads();
  if (tid < 20) {
    float a = 0.f;
    #pragma unroll
    for (int n = 0; n < 20; ++n)
      a += sh_w[n] * luts[(s*60 + n*3 + ch)*20 + tid];
    sh_v[tid] = a;
  }
  __syncthreads();
  const int q = qb*256 + tid;
  if (q < 1089) {
    float a = 0.f;
    #pragma unroll
    for (int w = 0; w < 20; ++w) a += sh_v[w] * wl[w*1089 + q];
    U[(size_t)(bt*15 + j)*1089 + q] = a;
  }
}

// ---------------- fused lutc+expand: block = (bt, bi-plane), both planes in LDS -------------
__global__ __launch_bounds__(256) void lut_fuse_kernel(
    const float* __restrict__ U, const float* __restrict__ slay, uint4* __restrict__ lut64)
{
  __shared__ uint2 s_lutc[2*1089];
  __shared__ float s_slay[165];
  const int tid = threadIdx.x;
  const int lin = blockIdx.x;            // bt + 8*bi, 264 blocks
  const int bt = lin & 7;
  const int bi = lin >> 3;               // 0..32
  if (tid < 165) s_slay[tid] = slay[tid];
  __syncthreads();
  const float* Ub = U + (size_t)bt*15*1089;
  for (int e = tid; e < 2*1089; e += 256) {
    int p = e / 1089, idx = e - p*1089;
    int bb = bi + p; if (bb > 32) bb = 32;
    int gi = idx / 33, ri = idx - gi*33;
    float v0 = 0.f, v1 = 0.f, v2 = 0.f;
    #pragma unroll
    for (int s = 0; s < 5; ++s) {
      v0 += s_slay[ri*5+s] * Ub[(s*3+0)*1089 + bb*33 + gi];
      v1 += s_slay[gi*5+s] * Ub[(s*3+1)*1089 + bb*33 + ri];
      v2 += s_slay[bb*5+s] * Ub[(s*3+2)*1089 + gi*33 + ri];
    }
    union { __half2 h2; unsigned u; } p0, p1;
    p0.h2 = __floats2half2_rn(v0, v1);
    p1.h2 = __floats2half2_rn(v2, 0.f);
    s_lutc[e] = make_uint2(p0.u, p1.u);
  }
  __syncthreads();
  for (int e = tid; e < 1089; e += 256) {
    int gi = e / 33, ri = e - gi*33;
    int g1 = gi < 32 ? gi+1 : 32, r1 = ri < 32 ? ri+1 : 32;
    union { unsigned short h[32]; uint4 q[4]; } u;
    #pragma unroll
    for (int t = 24; t < 32; ++t) u.h[t] = 0;
    const int gsel[2] = { gi, g1 }, rsel[2] = { ri, r1 };
    #pragma unroll
    for (int db = 0; db < 2; ++db)
      #pragma unroll
      for (int dg = 0; dg < 2; ++dg)
        #pragma unroll
        for (int dr = 0; dr < 2; ++dr) {
          const int idx = db*4 + dg*2 + dr;
          uint2 sv = s_lutc[db*1089 + gsel[dg]*33 + rsel[dr]];
          u.h[idx*3+0] = (unsigned short)(sv.x & 0xffff);
          u.h[idx*3+1] = (unsigned short)(sv.x >> 16);
          u.h[idx*3+2] = (unsigned short)(sv.y & 0xffff);
        }
    uint4* dst = lut64 + ((size_t)bt*35937 + bi*1089 + e)*4;
    dst[0] = u.q[0]; dst[1] = u.q[1]; dst[2] = u.q[2]; dst[3] = u.q[3];
  }
}

// ---------------- trilinear apply + residual: 1 cache line per pixel (round-10 form) --------
__global__ __launch_bounds__(256) void trilin_kernel(
    const float* __restrict__ img, const uint4* __restrict__ lut, float* __restrict__ out)
{
  constexpr int NPX = 720*1280;
  const int lin = blockIdx.x;
  const int bt = lin & 7;
  const int v = (lin >> 3)*256 + threadIdx.x;   // < NPX/4 exactly (900*256)
  const float* ib = img + (size_t)bt*3*NPX;
  float4 r4 = *((const float4*)ib + v);
  float4 g4 = *((const float4*)(ib + NPX) + v);
  float4 b4 = *((const float4*)(ib + 2*NPX) + v);
  const uint4* L = lut + (size_t)bt*35937*4;
  const float invbin = 32.0f/1.000001f;

  int base[4];
  float fr[4], fg[4], fb[4];
  #pragma unroll
  for (int j = 0; j < 4; ++j) {
    float r = ((float*)&r4)[j], g = ((float*)&g4)[j], b = ((float*)&b4)[j];
    float pr = r*invbin, pg = g*invbin, pb = b*invbin;
    int ri = (int)pr; ri = ri > 31 ? 31 : ri; ri = ri < 0 ? 0 : ri;
    int gi = (int)pg; gi = gi > 31 ? 31 : gi; gi = gi < 0 ? 0 : gi;
    int bi = (int)pb; bi = bi > 31 ? 31 : bi; bi = bi < 0 ? 0 : bi;
    fr[j] = pr - ri; fg[j] = pg - gi; fb[j] = pb - bi;
    base[j] = (bi*33 + gi)*33 + ri;
  }
  uint4 q0[4], q1[4], q2[4];
  #pragma unroll
  for (int j = 0; j < 4; ++j) {
    const uint4* e = L + (size_t)base[j]*4;
    q0[j] = e[0]; q1[j] = e[1]; q2[j] = e[2];
  }
  float4 ro, go, bo;
  float* rp = (float*)&ro; float* gp = (float*)&go; float* bp = (float*)&bo;
  #pragma unroll
  for (int j = 0; j < 4; ++j) {
    union { uint4 q[3]; __half h[24]; } u;
    u.q[0] = q0[j]; u.q[1] = q1[j]; u.q[2] = q2[j];
    float wr1 = fr[j], wr0 = 1.f-fr[j];
    float wg1 = fg[j], wg0 = 1.f-fg[j];
    float wb1 = fb[j], wb0 = 1.f-fb[j];
    float w00 = wb0*wg0, w01 = wb0*wg1, w10 = wb1*wg0, w11 = wb1*wg1;
    float wt[8] = { w00*wr0, w00*wr1, w01*wr0, w01*wr1,
                    w10*wr0, w10*wr1, w11*wr0, w11*wr1 };
    float rr = 0.f, gg = 0.f, bb2 = 0.f;
    #pragma unroll
    for (int idx = 0; idx < 8; ++idx) {
      float wv = wt[idx];
      rr  += wv * __half2float(u.h[idx*3+0]);
      gg  += wv * __half2float(u.h[idx*3+1]);
      bb2 += wv * __half2float(u.h[idx*3+2]);
    }
    rp[j] = rr  + ((float*)&r4)[j];
    gp[j] = gg  + ((float*)&g4)[j];
    bp[j] = bb2 + ((float*)&b4)[j];
  }
  float* ob = out + (size_t)bt*3*NPX;
  *((float4*)ob + v) = ro;
  *((float4*)(ob + NPX) + v) = go;
  *((float4*)(ob + 2*NPX) + v) = bo;
}

// ---------------- launcher ----------------
extern "C" void kernel_launch(void* const* d_in, const int* in_sizes, int n_in,
                              void* d_out, int out_size, void* d_ws, size_t ws_size,
                              hipStream_t stream) {
  const float* img     = (const float*)d_in[0];
  const float* img_org = (const float*)d_in[1];
  const float* c0w = (const float*)d_in[2];  const float* c0b = (const float*)d_in[3];
  const float* c1w = (const float*)d_in[4];  const float* c1b = (const float*)d_in[5];
  const float* c2w = (const float*)d_in[6];  const float* c2b = (const float*)d_in[7];
  const float* c3w = (const float*)d_in[8];  const float* c3b = (const float*)d_in[9];
  const float* c4w = (const float*)d_in[10]; const float* c4b = (const float*)d_in[11];
  const float* n0g = (const float*)d_in[12]; const float* n0b = (const float*)d_in[13];
  const float* n1g = (const float*)d_in[14]; const float* n1b = (const float*)d_in[15];
  const float* n2g = (const float*)d_in[16]; const float* n2b = (const float*)d_in[17];
  const float* n3g = (const float*)d_in[18]; const float* n3b = (const float*)d_in[19];
  const float* cls0_w = (const float*)d_in[20]; const float* cls0_b = (const float*)d_in[21];
  const float* cls1_w = (const float*)d_in[22]; const float* cls1_b = (const float*)d_in[23];
  const float* s_layers = (const float*)d_in[24];
  const float* w_layers = (const float*)d_in[25];
  const float* luts     = (const float*)d_in[26];
  float* ws = (float*)d_ws;
  float* out = (float*)d_out;

  // zero stats + featsum
  zero_k<<<19, 256, 0, stream>>>(ws + OFF_STATB, 4864);

  // conv0: 3->16.  TH=4 OCG=16 PX=8 OCT=2 -> BLK=512, grid 8*32 = 256 (round-10 config)
  conv_tile<3,16,256,256, 4,16, 8,2, 512, 0, 1><<<256, 512, 0, stream>>>(
      img, c0w, c0b, nullptr, nullptr, nullptr, ws + OFF_Y0, ws + OFF_STAT0);
  // conv1: 16->32. TH=1 OCG=32 PX=2 OCT=2 -> BLK=512, grid 8*64 = 512 (2 blocks/CU, 26 KB LDS)
  conv_tile<16,32,128,128, 1,32, 2,2, 512, 1, 16384><<<512, 512, 0, stream>>>(
      ws + OFF_Y0, c1w, c1b, ws + OFF_STAT0, n0g, n0b, ws + OFF_Y1, ws + OFF_STAT1);
  // conv2: 32->64. TH=1 OCG=32 PX=1 OCT=2 -> BLK=512, grid 8*32*2 = 512 (28 KB LDS)
  conv_tile<32,64,64,64, 1,32, 1,2, 512, 1, 4096><<<512, 512, 0, stream>>>(
      ws + OFF_Y1, c2w, c2b, ws + OFF_STAT1, n1g, n1b, ws + OFF_Y2, ws + OFF_STAT2);
  // conv3: 64->128. TH=1 OCG=32 PX=1 OCT=2 -> BLK=256, grid 8*16*4 = 512 (31 KB LDS)
  conv_tile<64,128,32,32, 1,32, 1,2, 256, 1, 1024><<<512, 256, 0, stream>>>(
      ws + OFF_Y2, c3w, c3b, ws + OFF_STAT2, n2g, n2b, ws + OFF_Y3, ws + OFF_STAT3);
  // conv4: 128->128, mean -> featsum. TH=2 OCG=16 PX=1 OCT=1 -> BLK=256, grid 256
  conv_tile<128,128,16,16, 2,16, 1,1, 256, 2, 256><<<256, 256, 0, stream>>>(
      ws + OFF_Y3, c4w, c4b, ws + OFF_STAT3, n3g, n3b, nullptr, ws + OFF_FEATS);

  // U directly from luts/wl with in-block head
  u_direct_kernel<<<600, 256, 0, stream>>>(
      ws + OFF_FEATS, cls0_w, cls0_b, cls1_w, cls1_b,
      luts, w_layers, ws + OFF_U);

  // fused lutc + expand
  lut_fuse_kernel<<<264, 256, 0, stream>>>(
      ws + OFF_U, s_layers, (uint4*)(ws + OFF_LUT64));

  trilin_kernel<<<900*8, 256, 0, stream>>>(
      img_org, (const uint4*)(ws + OFF_LUT64), out);
}

// Round 13
// 216.782 us; speedup vs baseline: 1.4262x; 1.2298x over previous
//
#include <hip/hip_runtime.h>
#include <hip/hip_fp16.h>

// ---------------- workspace layout (float offsets) ----------------
constexpr size_t OFF_Y0    = 0;         // 8*16*128*128 = 2097152
constexpr size_t OFF_Y1    = 2097152;   // 8*32*64*64   = 1048576
constexpr size_t OFF_Y2    = 3145728;   // 8*64*32*32   = 524288
constexpr size_t OFF_Y3    = 3670016;   // 8*128*16*16  = 262144 (ends 3932160)
constexpr size_t OFF_U     = 3670016;   // 8*15*1089 = 130680 (in dead Y3, after conv4 reads it)
constexpr size_t OFF_LUTC  = 0;         // compact fp16: 8*35937 uint2 = 574992 dwords (dead Y0)
constexpr size_t OFF_LUTQ  = 1048576;   // 10-bit codes: 8*35937 dwords = 287496 (dead Y0 tail)
constexpr size_t OFF_STATB = 4926640;
constexpr size_t OFF_STAT0 = OFF_STATB + 0;     // 8*16*2  = 256
constexpr size_t OFF_STAT1 = OFF_STATB + 256;   // 8*32*2  = 512
constexpr size_t OFF_STAT2 = OFF_STATB + 768;   // 8*64*2  = 1024
constexpr size_t OFF_STAT3 = OFF_STATB + 1792;  // 8*128*2 = 2048
constexpr size_t OFF_FEATS = OFF_STATB + 3840;  // 8*128   = 1024
constexpr size_t OFF_MAXB  = OFF_STATB + 4864;  // 8 per-batch absmax (uint-as-float)

__global__ __launch_bounds__(256) void zero_k(float* __restrict__ p, int n) {
  int i = blockIdx.x*256 + threadIdx.x;
  if (i < n) p[i] = 0.f;
}

// ---------------- unified tiled conv (round-10 config): stride-2 3x3 + lrelu ----------------
template<int CIN, int COUT, int HIN, int WIN, int TH, int OCG, int PX, int OCT,
         int BLK, int MODE, int NPXPREV>
__global__ __launch_bounds__(BLK) void conv_tile(
    const float* __restrict__ xin, const float* __restrict__ wgt,
    const float* __restrict__ bias, const float* __restrict__ stat_in,
    const float* __restrict__ gam, const float* __restrict__ bet,
    float* __restrict__ yout, float* __restrict__ stat_out)
{
  constexpr int HOUT = HIN/2, WOUT = WIN/2;
  constexpr int SEG  = WOUT + 4;
  constexpr int XROW = 2*SEG;
  constexpr int XPI  = (2*TH+1)*XROW;
  constexpr int NT   = HOUT/TH;
  constexpr int NSTRIP_B = TH*WOUT/PX;
  constexpr int GPT  = OCG/OCT;
  static_assert(BLK == NSTRIP_B*GPT, "thread mapping mismatch");
  constexpr int R = NSTRIP_B < 64 ? NSTRIP_B : 64;

  __shared__ __align__(16) float xs[CIN*XPI];
  __shared__ float s_sc[CIN], s_sf[CIN];

  const int tid = threadIdx.x;
  const int lin = blockIdx.x;
  const int b = lin & 7;
  const int r2 = lin >> 3;
  const int tile = r2 % NT;
  const int ocb  = r2 / NT;

  if constexpr (MODE == 0) {
    if (tid == 0)      { s_sc[0] = 1.f/0.229f; s_sf[0] = -0.485f/0.229f; }
    else if (tid == 1) { s_sc[1] = 1.f/0.224f; s_sf[1] = -0.456f/0.224f; }
    else if (tid == 2) { s_sc[2] = 1.f/0.225f; s_sf[2] = -0.406f/0.225f; }
  } else {
    if (tid < CIN) {
      float S = stat_in[(b*CIN+tid)*2+0], Q = stat_in[(b*CIN+tid)*2+1];
      float mean = S*(1.0f/NPXPREV);
      float var  = Q*(1.0f/NPXPREV) - mean*mean;
      float rstd = rsqrtf(var + 1e-5f);
      float gg = gam[tid], bb = bet[tid];
      s_sc[tid] = gg*rstd;
      s_sf[tid] = bb - mean*gg*rstd;
    }
  }
  __syncthreads();

  const int iy0 = tile*(2*TH) - 1;
  const float* xb_g = xin + (size_t)b*CIN*HIN*WIN;
  for (int e = tid; e < CIN*(2*TH+1)*(WIN+2); e += BLK) {
    int ic  = e / ((2*TH+1)*(WIN+2));
    int rem = e - ic*((2*TH+1)*(WIN+2));
    int rr  = rem / (WIN+2);
    int cc  = rem - rr*(WIN+2);
    int iy = iy0 + rr, ix = cc - 1;
    float v = 0.f;
    if (iy >= 0 && iy < HIN && ix >= 0 && ix < WIN)
      v = s_sc[ic]*xb_g[(size_t)ic*HIN*WIN + iy*WIN + ix] + s_sf[ic];
    int off = (ix & 1) ? (SEG + ((ix+1) >> 1)) : (ix >> 1);
    xs[ic*XPI + rr*XROW + off] = v;
  }
  __syncthreads();

  const int s  = tid % NSTRIP_B;
  const int g  = tid / NSTRIP_B;
  const int r  = s / (WOUT/PX);
  const int c0 = (s % (WOUT/PX)) * PX;
  const int oc0 = ocb*OCG + g*OCT;

  float acc[OCT][PX];
  #pragma unroll
  for (int k = 0; k < OCT; ++k) {
    float bb = bias[oc0+k];
    #pragma unroll
    for (int j = 0; j < PX; ++j) acc[k][j] = bb;
  }

  float wv[OCT][9];
  #pragma unroll
  for (int k = 0; k < OCT; ++k) {
    const float* wp = wgt + ((size_t)(oc0+k)*CIN)*9;
    #pragma unroll
    for (int t = 0; t < 9; ++t) wv[k][t] = wp[t];
  }

  for (int ic = 0; ic < CIN; ++ic) {
    float wn[OCT][9];
    if (ic + 1 < CIN) {
      #pragma unroll
      for (int k = 0; k < OCT; ++k) {
        const float* wp = wgt + ((size_t)(oc0+k)*CIN + ic + 1)*9;
        #pragma unroll
        for (int t = 0; t < 9; ++t) wn[k][t] = wp[t];
      }
    }
    const float* xb = xs + ic*XPI;
    #pragma unroll
    for (int ky = 0; ky < 3; ++ky) {
      const float* rowp = xb + (2*r+ky)*XROW;
      float eb[PX], ob[PX+1];
      if constexpr (PX == 8) {
        *(float4*)&eb[0] = *(const float4*)(rowp + c0);
        *(float4*)&eb[4] = *(const float4*)(rowp + c0 + 4);
        *(float4*)&ob[0] = *(const float4*)(rowp + SEG + c0);
        *(float4*)&ob[4] = *(const float4*)(rowp + SEG + c0 + 4);
        ob[8] = rowp[SEG + c0 + 8];
      } else if constexpr (PX == 4) {
        *(float4*)&eb[0] = *(const float4*)(rowp + c0);
        *(float4*)&ob[0] = *(const float4*)(rowp + SEG + c0);
        ob[4] = rowp[SEG + c0 + 4];
      } else if constexpr (PX == 2) {
        *(float2*)&eb[0] = *(const float2*)(rowp + c0);
        *(float2*)&ob[0] = *(const float2*)(rowp + SEG + c0);
        ob[2] = rowp[SEG + c0 + 2];
      } else {
        eb[0] = rowp[c0];
        ob[0] = rowp[SEG + c0];
        ob[1] = rowp[SEG + c0 + 1];
      }
      #pragma unroll
      for (int k = 0; k < OCT; ++k) {
        float w0 = wv[k][ky*3], w1 = wv[k][ky*3+1], w2 = wv[k][ky*3+2];
        #pragma unroll
        for (int j = 0; j < PX; ++j)
          acc[k][j] += w0*ob[j] + w1*eb[j] + w2*ob[j+1];
      }
    }
    if (ic + 1 < CIN) {
      #pragma unroll
      for (int k = 0; k < OCT; ++k)
        #pragma unroll
        for (int t = 0; t < 9; ++t) wv[k][t] = wn[k][t];
    }
  }

  const int oy = tile*TH + r;
  if constexpr (MODE != 2) {
    float lsum[OCT], lsq[OCT];
    #pragma unroll
    for (int k = 0; k < OCT; ++k) {
      float ov[PX];
      float ls = 0.f, lq = 0.f;
      #pragma unroll
      for (int j = 0; j < PX; ++j) {
        float a = acc[k][j];
        a = a >= 0.f ? a : 0.2f*a;
        ov[j] = a; ls += a; lq += a*a;
      }
      lsum[k] = ls; lsq[k] = lq;
      float* yp = yout + (((size_t)b*COUT + oc0 + k)*HOUT + oy)*WOUT + c0;
      if constexpr (PX == 8) {
        *(float4*)yp = *(float4*)&ov[0];
        *(float4*)(yp+4) = *(float4*)&ov[4];
      } else if constexpr (PX == 4) {
        *(float4*)yp = *(float4*)&ov[0];
      } else if constexpr (PX == 2) {
        *(float2*)yp = *(float2*)&ov[0];
      } else {
        *yp = ov[0];
      }
    }
    #pragma unroll
    for (int k = 0; k < OCT; ++k) {
      #pragma unroll
      for (int off = R/2; off > 0; off >>= 1) {
        lsum[k] += __shfl_down(lsum[k], off);
        lsq[k]  += __shfl_down(lsq[k],  off);
      }
    }
    if ((tid & (R-1)) == 0) {
      #pragma unroll
      for (int k = 0; k < OCT; ++k) {
        atomicAdd(&stat_out[(b*COUT + oc0 + k)*2 + 0], lsum[k]);
        atomicAdd(&stat_out[(b*COUT + oc0 + k)*2 + 1], lsq[k]);
      }
    }
  } else {
    float a = acc[0][0];
    a = a >= 0.f ? a : 0.2f*a;
    #pragma unroll
    for (int off = R/2; off > 0; off >>= 1) a += __shfl_down(a, off);
    if ((tid & (R-1)) == 0) atomicAdd(&stat_out[b*COUT + oc0], a);
  }
}

// ---------------- U direct: head (redundant per block) + V fold + U slice ----------------
__global__ __launch_bounds__(256) void u_direct_kernel(
    const float* __restrict__ featsum, const float* __restrict__ w0, const float* __restrict__ b0,
    const float* __restrict__ w1, const float* __restrict__ b1,
    const float* __restrict__ luts, const float* __restrict__ wl, float* __restrict__ U)
{
  __shared__ float sh_h[128];
  __shared__ float sh_w[20];
  __shared__ float sh_v[20];
  const int tid = threadIdx.x;
  const int lin = blockIdx.x;            // bt + 8*(j*5+qb), 600 blocks
  const int bt = lin & 7;
  const int rest = lin >> 3;             // 0..74
  const int j = rest / 5, qb = rest % 5;
  const int s = j / 3, ch = j % 3;

  if (tid < 128) {
    const float* f = featsum + bt*128;
    const float* w = w0 + tid*128;
    float a = 0.f;
    for (int k = 0; k < 128; ++k) a += f[k]*w[k];
    a = b0[tid] + a*(1.0f/64.0f);
    float c = fminf(fmaxf(a + 3.f, 0.f), 6.f);
    sh_h[tid] = a * c * (1.f/6.f);
  }
  __syncthreads();
  if (tid < 20) {
    const float* w = w1 + tid*128;
    float a = b1[tid];
    for (int k = 0; k < 128; ++k) a += sh_h[k]*w[k];
    sh_w[tid] = a;
  }
  __syncthreads();
  if (tid < 20) {
    float a = 0.f;
    #pragma unroll
    for (int n = 0; n < 20; ++n)
      a += sh_w[n] * luts[(s*60 + n*3 + ch)*20 + tid];
    sh_v[tid] = a;
  }
  __syncthreads();
  const int q = qb*256 + tid;
  if (q < 1089) {
    float a = 0.f;
    #pragma unroll
    for (int w = 0; w < 20; ++w) a += sh_v[w] * wl[w*1089 + q];
    U[(size_t)(bt*15 + j)*1089 + q] = a;
  }
}

// ---------------- compact fp16 LUT + per-batch absmax ----------------
__global__ __launch_bounds__(256) void lutc_max_kernel(
    const float* __restrict__ U, const float* __restrict__ slay,
    uint2* __restrict__ lutc, unsigned* __restrict__ maxbuf)
{
  __shared__ float s_slay[165];
  __shared__ unsigned s_max;
  const int tid = threadIdx.x;
  if (tid < 165) s_slay[tid] = slay[tid];
  if (tid == 0) s_max = 0u;
  __syncthreads();
  const int lin = blockIdx.x;            // bt + 8*chunk, 141*8 blocks
  const int bt = lin & 7;
  const int i = (lin >> 3)*256 + tid;
  if (i < 35937) {
    int bi = i / 1089, rem = i - bi*1089, gi = rem / 33, ri = rem - gi*33;
    const float* Ub = U + (size_t)bt*15*1089;
    float v0 = 0.f, v1 = 0.f, v2 = 0.f;
    #pragma unroll
    for (int s = 0; s < 5; ++s) {
      v0 += s_slay[ri*5+s] * Ub[(s*3+0)*1089 + bi*33 + gi];
      v1 += s_slay[gi*5+s] * Ub[(s*3+1)*1089 + bi*33 + ri];
      v2 += s_slay[bi*5+s] * Ub[(s*3+2)*1089 + gi*33 + ri];
    }
    union { __half2 h2; unsigned u; } p0, p1;
    p0.h2 = __floats2half2_rn(v0, v1);
    p1.h2 = __floats2half2_rn(v2, 0.f);
    lutc[(size_t)bt*35937 + i] = make_uint2(p0.u, p1.u);
    float m = fmaxf(fmaxf(fabsf(v0), fabsf(v1)), fabsf(v2));
    atomicMax(&s_max, __float_as_uint(m));   // nonneg floats: uint cmp == float cmp
  }
  __syncthreads();
  if (tid == 0) atomicMax(&maxbuf[bt], s_max);
}

// ---------------- quantize compact fp16 -> 3x10-bit codes (4B/corner) ----------------
__global__ __launch_bounds__(256) void lutq_kernel(
    const uint2* __restrict__ lutc, const unsigned* __restrict__ maxbuf,
    unsigned* __restrict__ lutq)
{
  const int lin = blockIdx.x;            // bt + 8*chunk, 141*8 blocks
  const int bt = lin & 7;
  const int i = (lin >> 3)*256 + threadIdx.x;
  if (i >= 35937) return;
  float maxv = __uint_as_float(maxbuf[bt]);
  float enc = maxv > 0.f ? 511.0f/maxv : 0.f;
  uint2 c = lutc[(size_t)bt*35937 + i];
  __half2 h01 = *(__half2*)&c.x;
  __half2 h2_ = *(__half2*)&c.y;
  float v0 = __low2float(h01), v1 = __high2float(h01), v2 = __low2float(h2_);
  int q0 = (int)rintf(v0*enc) + 512;
  int q1 = (int)rintf(v1*enc) + 512;
  int q2 = (int)rintf(v2*enc) + 512;
  q0 = q0 < 0 ? 0 : (q0 > 1023 ? 1023 : q0);
  q1 = q1 < 0 ? 0 : (q1 > 1023 ? 1023 : q1);
  q2 = q2 < 0 ? 0 : (q2 > 1023 ? 1023 : q2);
  lutq[(size_t)bt*35937 + i] = (unsigned)q0 | ((unsigned)q1 << 10) | ((unsigned)q2 << 20);
}

// ---------------- trilinear from LDS-resident quantized LUT + residual ----------------
__device__ __forceinline__ void pair_acc(unsigned ca, unsigned cb, float wp, float fr,
                                         float& a0, float& a1, float& a2)
{
  float q0a = (float)(ca & 1023u), q1a = (float)((ca >> 10) & 1023u), q2a = (float)((ca >> 20) & 1023u);
  float q0b = (float)(cb & 1023u), q1b = (float)((cb >> 10) & 1023u), q2b = (float)((cb >> 20) & 1023u);
  a0 += wp * (q0a + fr*(q0b - q0a));
  a1 += wp * (q1a + fr*(q1b - q1a));
  a2 += wp * (q2a + fr*(q2b - q2a));
}

__global__ __launch_bounds__(1024) void trilin_lds_kernel(
    const float* __restrict__ img, const unsigned* __restrict__ lutq,
    const unsigned* __restrict__ maxbuf, float* __restrict__ out)
{
  constexpr int NPX = 720*1280;
  constexpr int NV4 = NPX/4;            // 230400
  constexpr int PER_BLK = NV4/32;       // 7200 float4-groups per block
  __shared__ unsigned s_lut[35937];     // 143,748 B

  const int tid = threadIdx.x;
  const int lin = blockIdx.x;           // bt + 8*bb, 256 blocks
  const int bt = lin & 7;
  const int bb = lin >> 3;              // 0..31
  const unsigned* Lg = lutq + (size_t)bt*35937;
  for (int i = tid; i < 35937; i += 1024) s_lut[i] = Lg[i];
  __syncthreads();

  const float maxv  = __uint_as_float(maxbuf[bt]);
  const float scale = maxv * (1.0f/511.0f);
  const float offc  = -512.0f * scale;
  const float* ib = img + (size_t)bt*3*NPX;
  float* ob = out + (size_t)bt*3*NPX;
  const float invbin = 32.0f/1.000001f;
  const int vend = bb*PER_BLK + PER_BLK;

  for (int v = bb*PER_BLK + tid; v < vend; v += 1024) {
    float4 r4 = ((const float4*)ib)[v];
    float4 g4 = ((const float4*)(ib + NPX))[v];
    float4 b4 = ((const float4*)(ib + 2*NPX))[v];
    float4 ro, go, bo;
    float* rp = (float*)&ro; float* gp = (float*)&go; float* bp = (float*)&bo;
    #pragma unroll
    for (int j = 0; j < 4; ++j) {
      float r = ((float*)&r4)[j], g = ((float*)&g4)[j], b = ((float*)&b4)[j];
      float pr = r*invbin, pg = g*invbin, pb = b*invbin;
      int ri = (int)pr; ri = ri > 31 ? 31 : ri; ri = ri < 0 ? 0 : ri;
      int gi = (int)pg; gi = gi > 31 ? 31 : gi; gi = gi < 0 ? 0 : gi;
      int bi = (int)pb; bi = bi > 31 ? 31 : bi; bi = bi < 0 ? 0 : bi;
      float fr = pr - ri, fg = pg - gi, fb = pb - bi;
      int i00 = (bi*33 + gi)*33 + ri;
      unsigned c00a = s_lut[i00],        c00b = s_lut[i00 + 1];
      unsigned c01a = s_lut[i00 + 33],   c01b = s_lut[i00 + 34];
      unsigned c10a = s_lut[i00 + 1089], c10b = s_lut[i00 + 1090];
      unsigned c11a = s_lut[i00 + 1122], c11b = s_lut[i00 + 1123];
      float wb0 = 1.f - fb, wb1 = fb, wg0 = 1.f - fg, wg1 = fg;
      float a0 = 0.f, a1 = 0.f, a2 = 0.f;
      pair_acc(c00a, c00b, wb0*wg0, fr, a0, a1, a2);
      pair_acc(c01a, c01b, wb0*wg1, fr, a0, a1, a2);
      pair_acc(c10a, c10b, wb1*wg0, fr, a0, a1, a2);
      pair_acc(c11a, c11b, wb1*wg1, fr, a0, a1, a2);
      rp[j] = a0*scale + offc + r;
      gp[j] = a1*scale + offc + g;
      bp[j] = a2*scale + offc + b;
    }
    ((float4*)ob)[v]           = ro;
    ((float4*)(ob + NPX))[v]   = go;
    ((float4*)(ob + 2*NPX))[v] = bo;
  }
}

// ---------------- launcher ----------------
extern "C" void kernel_launch(void* const* d_in, const int* in_sizes, int n_in,
                              void* d_out, int out_size, void* d_ws, size_t ws_size,
                              hipStream_t stream) {
  const float* img     = (const float*)d_in[0];
  const float* img_org = (const float*)d_in[1];
  const float* c0w = (const float*)d_in[2];  const float* c0b = (const float*)d_in[3];
  const float* c1w = (const float*)d_in[4];  const float* c1b = (const float*)d_in[5];
  const float* c2w = (const float*)d_in[6];  const float* c2b = (const float*)d_in[7];
  const float* c3w = (const float*)d_in[8];  const float* c3b = (const float*)d_in[9];
  const float* c4w = (const float*)d_in[10]; const float* c4b = (const float*)d_in[11];
  const float* n0g = (const float*)d_in[12]; const float* n0b = (const float*)d_in[13];
  const float* n1g = (const float*)d_in[14]; const float* n1b = (const float*)d_in[15];
  const float* n2g = (const float*)d_in[16]; const float* n2b = (const float*)d_in[17];
  const float* n3g = (const float*)d_in[18]; const float* n3b = (const float*)d_in[19];
  const float* cls0_w = (const float*)d_in[20]; const float* cls0_b = (const float*)d_in[21];
  const float* cls1_w = (const float*)d_in[22]; const float* cls1_b = (const float*)d_in[23];
  const float* s_layers = (const float*)d_in[24];
  const float* w_layers = (const float*)d_in[25];
  const float* luts     = (const float*)d_in[26];
  float* ws = (float*)d_ws;
  float* out = (float*)d_out;

  // zero stats + featsum + maxbuf
  zero_k<<<20, 256, 0, stream>>>(ws + OFF_STATB, 4872);

  // convs: round-10 config (best known)
  conv_tile<3,16,256,256, 4,16, 8,2, 512, 0, 1><<<256, 512, 0, stream>>>(
      img, c0w, c0b, nullptr, nullptr, nullptr, ws + OFF_Y0, ws + OFF_STAT0);
  conv_tile<16,32,128,128, 2,32, 4,2, 512, 1, 16384><<<256, 512, 0, stream>>>(
      ws + OFF_Y0, c1w, c1b, ws + OFF_STAT0, n0g, n0b, ws + OFF_Y1, ws + OFF_STAT1);
  conv_tile<32,64,64,64, 2,32, 2,2, 512, 1, 4096><<<256, 512, 0, stream>>>(
      ws + OFF_Y1, c2w, c2b, ws + OFF_STAT1, n1g, n1b, ws + OFF_Y2, ws + OFF_STAT2);
  conv_tile<64,128,32,32, 2,32, 1,2, 512, 1, 1024><<<256, 512, 0, stream>>>(
      ws + OFF_Y2, c3w, c3b, ws + OFF_STAT2, n2g, n2b, ws + OFF_Y3, ws + OFF_STAT3);
  conv_tile<128,128,16,16, 2,16, 1,1, 256, 2, 256><<<256, 256, 0, stream>>>(
      ws + OFF_Y3, c4w, c4b, ws + OFF_STAT3, n3g, n3b, nullptr, ws + OFF_FEATS);

  // U directly from luts/wl with in-block head
  u_direct_kernel<<<600, 256, 0, stream>>>(
      ws + OFF_FEATS, cls0_w, cls0_b, cls1_w, cls1_b,
      luts, w_layers, ws + OFF_U);

  // compact fp16 LUT + per-batch absmax
  lutc_max_kernel<<<141*8, 256, 0, stream>>>(
      ws + OFF_U, s_layers, (uint2*)(ws + OFF_LUTC), (unsigned*)(ws + OFF_MAXB));

  // quantize to 3x10-bit codes
  lutq_kernel<<<141*8, 256, 0, stream>>>(
      (const uint2*)(ws + OFF_LUTC), (const unsigned*)(ws + OFF_MAXB),
      (unsigned*)(ws + OFF_LUTQ));

  // trilinear from LDS-resident code table
  trilin_lds_kernel<<<256, 1024, 0, stream>>>(
      img_org, (const unsigned*)(ws + OFF_LUTQ), (const unsigned*)(ws + OFF_MAXB), out);
}